// Round 7
// baseline (98.462 us; speedup 1.0000x reference)
//
#include <hip/hip_runtime.h>
#include <hip/hip_fp16.h>
#include <math.h>

// Problem constants: B=8, T=64, R=100, TH=768, IH=1024, P=N=512
#define B_  8
#define T_  64
#define R_  100
#define TH_ 768
#define IH_ 1024
#define P_  512
#define N_  512

#define CTANH 2.88539008177792681f   // 2*log2(e): tanh(x) = 1 - 2/(1+exp2(CTANH*x))

typedef short short8  __attribute__((ext_vector_type(8)));
typedef float floatx4 __attribute__((ext_vector_type(4)));

__device__ __forceinline__ ushort f2bf(float f) {
  union { float f; unsigned int u; } v; v.f = f;
  unsigned int r = v.u + 0x7FFFu + ((v.u >> 16) & 1u);   // RNE
  return (ushort)(r >> 16);
}

// ---------------------------------------------------------------------------
// MFMA bf16 GEMM + bias + exact GELU -> f16 out (pre-scaled by CTANH).
// In-block split-K=4: 1024 threads = 4 splits x 4 waves. Tile 64m x 32n.
// UNCHANGED from round 6 (single-variable discipline: only fuse changes).
// ---------------------------------------------------------------------------
#define PADK 40

__global__ __launch_bounds__(1024) void mfma_linear_gelu_sk4(
    const float* __restrict__ encT, const float* __restrict__ Wq,
    const float* __restrict__ bq, __half* __restrict__ qout,
    const float* __restrict__ encI, const float* __restrict__ Wk,
    const float* __restrict__ bk, __half* __restrict__ kout) {
  const int rt = blockIdx.y;
  const bool isQ = rt < 8;
  const float* __restrict__ X = isQ ? encT : encI;
  const float* __restrict__ W = isQ ? Wq : Wk;
  const float* __restrict__ bias = isQ ? bq : bk;
  __half* __restrict__ Y = isQ ? qout : kout;
  const int M    = isQ ? (B_ * T_) : (B_ * R_);
  const int KDIM = isQ ? TH_ : IH_;
  const int row0 = (isQ ? rt : (rt - 8)) * 64;
  const int col0 = blockIdx.x * 32;
  const int kq   = KDIM >> 2;              // k-quarter: 192 or 256
  const int ntiles = kq / 32;              // 6 (Q) or 8 (K)

  __shared__ ushort As[4][64 * PADK];
  __shared__ ushort Bs[4][32 * PADK];
  __shared__ float  red[2][64 * 33];

  const int tid = threadIdx.x;
  const int sp  = tid >> 8;
  const int t   = tid & 255;
  const int kbase = sp * kq;

  const int arow = t >> 2;
  const int akq  = (t & 3) * 8;
  const int arowc = min(row0 + arow, M - 1);
  const float* __restrict__ Xp = X + (size_t)arowc * KDIM + kbase + akq;

  const int bkp = (t >> 4) * 2;
  const int bn2 = (t & 15) * 2;
  const float* __restrict__ Wp = W + (size_t)(kbase + bkp) * N_ + col0 + bn2;

  const int wv = t >> 6;
  const int lane = t & 63;
  const int wm = wv * 16;
  const int l15 = lane & 15;
  const int q8  = (lane >> 4) * 8;
  const int q4  = (lane >> 4) * 4;

  floatx4 acc0 = {0.f,0.f,0.f,0.f}, acc1 = {0.f,0.f,0.f,0.f};

  float4 a0 = *(const float4*)(Xp);
  float4 a1 = *(const float4*)(Xp + 4);
  float2 b0 = *(const float2*)(Wp);
  float2 b1 = *(const float2*)(Wp + N_);

  for (int kt = 0; kt < ntiles; ++kt) {
    {
      short8 pk;
      pk[0] = (short)f2bf(a0.x); pk[1] = (short)f2bf(a0.y);
      pk[2] = (short)f2bf(a0.z); pk[3] = (short)f2bf(a0.w);
      pk[4] = (short)f2bf(a1.x); pk[5] = (short)f2bf(a1.y);
      pk[6] = (short)f2bf(a1.z); pk[7] = (short)f2bf(a1.w);
      *(short8*)&As[sp][arow * PADK + akq] = pk;
    }
    {
      unsigned int p0 = (unsigned int)f2bf(b0.x) | ((unsigned int)f2bf(b1.x) << 16);
      unsigned int p1 = (unsigned int)f2bf(b0.y) | ((unsigned int)f2bf(b1.y) << 16);
      *(unsigned int*)&Bs[sp][(bn2 + 0) * PADK + bkp] = p0;
      *(unsigned int*)&Bs[sp][(bn2 + 1) * PADK + bkp] = p1;
    }
    __syncthreads();

    if (kt + 1 < ntiles) {
      const int kb = (kt + 1) * 32;
      a0 = *(const float4*)(Xp + kb);
      a1 = *(const float4*)(Xp + kb + 4);
      b0 = *(const float2*)(Wp + (size_t)kb * N_);
      b1 = *(const float2*)(Wp + (size_t)(kb + 1) * N_);
    }

    short8 af  = *(const short8*)&As[sp][(wm + l15) * PADK + q8];
    short8 bf0 = *(const short8*)&Bs[sp][(l15) * PADK + q8];
    short8 bf1 = *(const short8*)&Bs[sp][(16 + l15) * PADK + q8];
    acc0 = __builtin_amdgcn_mfma_f32_16x16x32_bf16(af, bf0, acc0, 0, 0, 0);
    acc1 = __builtin_amdgcn_mfma_f32_16x16x32_bf16(af, bf1, acc1, 0, 0, 0);
    __syncthreads();
  }

  if (sp >= 2) {
    float* L = red[sp - 2];
    #pragma unroll
    for (int j = 0; j < 4; ++j) {
      L[(wm + q4 + j) * 33 + l15]      = acc0[j];
      L[(wm + q4 + j) * 33 + 16 + l15] = acc1[j];
    }
  }
  __syncthreads();
  if (sp < 2) {
    const float* L = red[sp];
    #pragma unroll
    for (int j = 0; j < 4; ++j) {
      acc0[j] += L[(wm + q4 + j) * 33 + l15];
      acc1[j] += L[(wm + q4 + j) * 33 + 16 + l15];
    }
  }
  __syncthreads();
  if (sp == 1) {
    float* L = red[0];
    #pragma unroll
    for (int j = 0; j < 4; ++j) {
      L[(wm + q4 + j) * 33 + l15]      = acc0[j];
      L[(wm + q4 + j) * 33 + 16 + l15] = acc1[j];
    }
  }
  __syncthreads();
  if (sp == 0) {
    const float* L = red[0];
    const float is2 = 0.70710678118654752f;
    const float bia0 = bias[col0 + l15];
    const float bia1 = bias[col0 + 16 + l15];
    #pragma unroll
    for (int j = 0; j < 4; ++j) {
      const int row = row0 + wm + q4 + j;
      if (row < M) {
        float v0 = acc0[j] + L[(wm + q4 + j) * 33 + l15] + bia0;
        float v1 = acc1[j] + L[(wm + q4 + j) * 33 + 16 + l15] + bia1;
        v0 = CTANH * 0.5f * v0 * (1.f + erff(v0 * is2));
        v1 = CTANH * 0.5f * v1 * (1.f + erff(v1 * is2));
        Y[(size_t)row * N_ + col0 + l15]      = __float2half(v0);
        Y[(size_t)row * N_ + col0 + 16 + l15] = __float2half(v1);
      }
    }
  }
}

// ---------------------------------------------------------------------------
// Fusion v3 with k-row reuse across a 16-t tile.
// Grid (32 = 8b x 4 tgroups, 25 r-groups) x 256 thr = 800 blocks.
// Block: stage 16 q-rows (f16, 16 KB LDS). One wave = one r: its k-row is
// loaded ONCE (16 B/lane) and swept across 16 t's from LDS.
// k traffic: 52 MB -> 3.2 MB. Per elem: hadd2/2 + cvt + add + exp + rcp + fma,
// out = sumw - 2*sum(w*d) (sumw folded out of the inner loop).
// ---------------------------------------------------------------------------
__global__ __launch_bounds__(256) void fuse_kernel_t16(
    const __half* __restrict__ q, const __half* __restrict__ k,
    const float* __restrict__ w, const float* __restrict__ bscalar,
    const float* __restrict__ mask, float* __restrict__ out) {
  const int bx = blockIdx.x;            // 0..31
  const int b  = bx >> 2;
  const int t0 = (bx & 3) * 16;
  const int wave = threadIdx.x >> 6;
  const int lane = threadIdx.x & 63;
  const int r = blockIdx.y * 4 + wave;  // 0..99

  __shared__ __half qs[16 * 512];       // 16 KB

  // stage 16 contiguous q rows: 16 KB, 64 B per thread
  {
    const float4* __restrict__ src =
        (const float4*)(q + (size_t)(b * 64 + t0) * 512);
    float4* dst = (float4*)qs;
    #pragma unroll
    for (int i = 0; i < 4; ++i)
      dst[threadIdx.x + 256 * i] = src[threadIdx.x + 256 * i];
  }

  // this wave's k row: 16 B per lane, issued before the barrier
  union { float4 f; __half2 h[4]; } ku;
  ku.f = *(const float4*)(k + ((size_t)(b * R_ + r) << 9) + lane * 8);

  // w slice in registers + block-wide sum of w
  float wr[8];
  *(float4*)&wr[0] = *(const float4*)(w + lane * 8);
  *(float4*)&wr[4] = *(const float4*)(w + lane * 8 + 4);
  float sumw = wr[0] + wr[1] + wr[2] + wr[3] + wr[4] + wr[5] + wr[6] + wr[7];
  #pragma unroll
  for (int off = 1; off < 64; off <<= 1) sumw += __shfl_xor(sumw, off, 64);

  __syncthreads();

  float res = 0.f;
  #pragma unroll
  for (int tt = 0; tt < 16; ++tt) {
    union { float4 f; __half2 h[4]; } qu;
    qu.f = *(const float4*)(qs + tt * 512 + lane * 8);
    float accd0 = 0.f, accd1 = 0.f;
    #pragma unroll
    for (int e = 0; e < 4; ++e) {
      __half2 s = __hadd2(qu.h[e], ku.h[e]);
      float x0 = __low2float(s);
      float x1 = __high2float(s);
      float d0 = __builtin_amdgcn_rcpf(1.f + __builtin_amdgcn_exp2f(x0));
      float d1 = __builtin_amdgcn_rcpf(1.f + __builtin_amdgcn_exp2f(x1));
      accd0 = fmaf(wr[2 * e],     d0, accd0);
      accd1 = fmaf(wr[2 * e + 1], d1, accd1);
    }
    float accd = accd0 + accd1;
    #pragma unroll
    for (int off = 1; off < 64; off <<= 1) accd += __shfl_xor(accd, off, 64);
    res = (lane == tt) ? accd : res;    // lane tt keeps t=tt's reduction
  }

  if (lane < 16) {
    const int bt = b * 64 + t0 + lane;
    const size_t o = (size_t)bt * R_ + r;
    out[o] = sumw - 2.f * res + bscalar[0] + mask[o];
  }
}

// ---------------------------------------------------------------------------
extern "C" void kernel_launch(void* const* d_in, const int* in_sizes, int n_in,
                              void* d_out, int out_size, void* d_ws, size_t ws_size,
                              hipStream_t stream) {
  const float* encT = (const float*)d_in[0];
  const float* encI = (const float*)d_in[1];
  const float* mask = (const float*)d_in[2];
  const float* Wq   = (const float*)d_in[3];
  const float* bq   = (const float*)d_in[4];
  const float* Wk   = (const float*)d_in[5];
  const float* bk   = (const float*)d_in[6];
  const float* w    = (const float*)d_in[7];
  const float* bsc  = (const float*)d_in[8];
  float* out = (float*)d_out;

  __half* q = (__half*)d_ws;               // [512, 512] f16, CTANH-prescaled
  __half* k = q + (size_t)B_ * T_ * P_;    // [800, 512] f16, CTANH-prescaled

  dim3 grid(N_ / 32, 8 + 13);              // 336 blocks x 1024 threads
  mfma_linear_gelu_sk4<<<grid, 1024, 0, stream>>>(encT, Wq, bq, q,
                                                  encI, Wk, bk, k);

  fuse_kernel_t16<<<dim3(32, 25), 256, 0, stream>>>(q, k, w, bsc, mask, out);
}